// Round 7
// baseline (296.166 us; speedup 1.0000x reference)
//
#include <hip/hip_runtime.h>
#include <math.h>

// DiffKS round 10.
// r9 post-mortem: adaptive chunking DID cut serial steps, but two VMEM
// drains landed on the chain: (a) vmcnt(0) after COMPUTE also drained the
// just-issued out[] stores (~400 cy/step); (b) staging was issued in the
// same step as its drain -> zero prefetch slack (~600 cy/staging step).
// r10 keeps the adaptive-chunk skeleton and removes both:
//   * no global stores in the loop: output dumped from the history ring one
//     chunk behind (<=341 samples, 2 predicated stores/thread, never waited);
//   * counted vmcnt publish: stage-ahead chunk k+5, publish-need chunk k+3
//     (2-step slack), end-of-step wait vmcnt(6*nn) with nn = newer blocks
//     (wave-uniform 0/6/12/18 branch); in-order vmcnt retirement guarantees
//     the needed block completed while newest staging stays in flight;
//   * chunk length cap 497 -> 341 (3 chunks <= 1023) keeps the 4-slot coef
//     ring and ring-dump aliasing safe at +5 stage-ahead (costs ~3% length
//     on ~3% of chunks).
// Per-sample math bit-identical to r7/r8/r9.

#define T_SAMPLES 44100
#define NFRAMES   100
#define NCOEF     6
#define BURST     2048
#define EXC_ORD   5

#define BLKF      6144          // 512 samples * 12 floats per coef block
#define HISTSZ    1096          // 1024 ring + 6 mirror + pad + 64 dump
#define MAXCH     448
#define LCAP      341

#define WS_COEF_FLOATS (T_SAMPLES * 12)
#define WS_EXC_OFF     WS_COEF_FLOATS
#define WS_EXC_FLOATS  (EXC_ORD * BURST)
#define WS_TOTAL_BYTES ((size_t)(WS_COEF_FLOATS + WS_EXC_FLOATS) * 4)

// ---------------------------------------------------------------- kernel A
__global__ __launch_bounds__(256) void diffks_precompute(
    const float* __restrict__ delay_frames,
    const float* __restrict__ raw_coeff,
    const float* __restrict__ raw_gain,
    const float* __restrict__ exc_coeff,
    float* __restrict__ ws)
{
    int g = blockIdx.x * 256 + threadIdx.x;
    const float gain = 0.1f / (1.0f + expf(-raw_gain[0])) + 0.9f;

    if (g < T_SAMPLES) {
        const float stepT = 99.0f / (float)(T_SAMPLES - 1);
        float pos = (float)g * stepT;
        int i0 = (int)pos; if (i0 > NFRAMES - 2) i0 = NFRAMES - 2;
        float w = pos - (float)i0;

        float d0 = delay_frames[i0], d1 = delay_frames[i0 + 1];
        float delay = d0 + (d1 - d0) * w;
        int z = (int)delay;                  // delay >= 100 > 0
        float alfa = delay - (float)z;

        float b[NCOEF];
        {
            float c0v[NCOEF], c1v[NCOEF];
            float s0 = 0.f, s1 = 0.f;
            #pragma unroll
            for (int j = 0; j < NCOEF; ++j) {
                c0v[j] = 1.0f / (1.0f + expf(-raw_coeff[i0 * NCOEF + j]));
                c1v[j] = 1.0f / (1.0f + expf(-raw_coeff[(i0 + 1) * NCOEF + j]));
                s0 += c0v[j]; s1 += c1v[j];
            }
            float g0 = gain / s0, g1 = gain / s1;
            #pragma unroll
            for (int j = 0; j < NCOEF; ++j) {
                float x0 = c0v[j] * g0, x1 = c1v[j] * g1;
                b[j] = x0 + (x1 - x0) * w;
            }
        }
        // v_j exactly as previous rounds (bit-identical), then negate (exact)
        float oma = 1.0f - alfa;
        float v0 = -oma * b[0];
        float v1 = -(alfa * b[0] + oma * b[1]);
        float v2 = -(alfa * b[1] + oma * b[2]);
        float v3 = -(alfa * b[2] + oma * b[3]);
        float v4 = -(alfa * b[3] + oma * b[4]);
        float v5 = -(alfa * b[4] + oma * b[5]);
        float v6 = -alfa * b[5];
        float pv0 = -v0, pv1 = -v1, pv2 = -v2, pv3 = -v3;
        float pv4 = -v4, pv5 = -v5, pv6 = -v6;

        int base = g - z - 1;
        int q = base - 6;                    // window = y[q .. q+6]
        int off = q & 1;
        unsigned b2 = ((unsigned)q) & 1022u; // (q & ~1) & 1023, 8B-aligned

        // shifted taps: m[off+6-j] = pv_j  (FMA iterates i = 7..0)
        float m0, m1, m2, m3, m4, m5, m6, m7;
        if (off) { m0 = 0.f; m1 = pv6; m2 = pv5; m3 = pv4;
                   m4 = pv3; m5 = pv2; m6 = pv1; m7 = pv0; }
        else     { m0 = pv6; m1 = pv5; m2 = pv4; m3 = pv3;
                   m4 = pv2; m5 = pv1; m6 = pv0; m7 = 0.f; }

        float4* o = (float4*)(ws + (size_t)g * 12);
        o[0] = make_float4(m0, m1, m2, m3);
        o[1] = make_float4(m4, m5, m6, m7);
        o[2] = make_float4(__int_as_float((int)b2), 0.f, 0.f, 0.f);
    } else if (g < T_SAMPLES + BURST) {
        int te = g - T_SAMPLES;
        const float stepE = 99.0f / (float)(BURST - 1);
        float pos = (float)te * stepE;
        int i0 = (int)pos; if (i0 > NFRAMES - 2) i0 = NFRAMES - 2;
        float w = pos - (float)i0;
        float* o = ws + WS_EXC_OFF + te * EXC_ORD;     // interleaved [t*5+k]
        #pragma unroll
        for (int k = 0; k < EXC_ORD; ++k) {
            float a0 = exc_coeff[i0 * EXC_ORD + k];
            float a1 = exc_coeff[(i0 + 1) * EXC_ORD + k];
            o[k] = a0 + (a1 - a0) * w;
        }
    }
}

// async global->LDS copy, 16B per lane; LDS base must be wave-uniform
__device__ __forceinline__ void gload_lds16(const float* g, float* l) {
    __builtin_amdgcn_global_load_lds(
        (const __attribute__((address_space(1))) unsigned int*)(g),
        (__attribute__((address_space(3))) unsigned int*)(l),
        16, 0, 0);
}

// ---------------------------------------------------------------- kernel B
__global__ __launch_bounds__(256, 1) void diffks_serial(
    const float* __restrict__ delay_frames,
    const float* __restrict__ excitation,
    const float* __restrict__ ws,
    float* __restrict__ out)
{
    __shared__ float s_big[24576];       // coef ring (phase2) / s_a+tails (ph1)
    __shared__ float s_x[64][33];        // burst (padded rows)
    __shared__ float s_hist[HISTSZ];     // 1024 ring + 6 mirror + 64 dump
    __shared__ int   s_cs[MAXCH];        // chunk starts (cs[NCH] = 44100)
    __shared__ int   s_zmin[100];
    __shared__ int   s_mf[100];
    __shared__ int   s_nch;

    float (* const s_a)[161]  = (float(*)[161])(s_big);          // 10304 f
    float (* const s_tail)[32] = (float(*)[32])(s_big + 10304);  // 2048 f
    float (* const s_bound)[6] = (float(*)[6])(s_big + 12352);   // 384 f

    const int tid  = threadIdx.x;
    const int lane = tid & 63;
    const int wv   = tid >> 6;

    // ---- stage (all 256 threads) ----
    for (int t = tid; t < BURST; t += 256)
        s_x[t >> 5][t & 31] = excitation[t];
    for (int i = 0; i < 8; ++i) {        // exc coefs, 5 contiguous scalars
        int t = tid + i * 256;
        const float* g = ws + WS_EXC_OFF + t * EXC_ORD;
        float* dst = &s_a[t >> 5][(t & 31) * 5];
        dst[0] = g[0]; dst[1] = g[1]; dst[2] = g[2];
        dst[3] = g[3]; dst[4] = g[4];
    }
    if (tid < 99) {                      // conservative per-frame z minimum
        float d0 = delay_frames[tid], d1 = delay_frames[tid + 1];
        s_zmin[tid] = (int)floorf(fminf(d0, d1));
    }
    for (int i = tid; i < HISTSZ; i += 256) s_hist[i] = 0.0f;
    __syncthreads();

    if (tid < 99) {                      // Mf[f] = min zmin over f..f+2
        int hi = tid + 2; if (hi > 98) hi = 98;
        int m = s_zmin[tid];
        for (int f = tid + 1; f <= hi; ++f) { int v = s_zmin[f]; if (v < m) m = v; }
        s_mf[tid] = m;
    }
    __syncthreads();

    // ---- phase 1 (wave 0) + greedy chunk scan (thread 192), overlapped ----
    if (tid < 64) {
        float st[6][5];
        #pragma unroll
        for (int r = 0; r < 6; ++r)
            #pragma unroll
            for (int k = 0; k < 5; ++k) st[r][k] = 0.0f;
        #pragma unroll
        for (int r = 1; r <= 5; ++r) st[r][r - 1] = 1.0f;

        const float* ar = &s_a[lane][0];
        const float* xr = &s_x[lane][0];
        #pragma unroll 8
        for (int i = 0; i < 32; ++i) {
            float a0 = ar[i * 5 + 0], a1 = ar[i * 5 + 1], a2 = ar[i * 5 + 2];
            float a3 = ar[i * 5 + 3], a4 = ar[i * 5 + 4];
            float xv = xr[i];
            #pragma unroll
            for (int r = 0; r < 6; ++r) {
                float acc = (r == 0) ? xv : 0.0f;
                acc = fmaf(-a0, st[r][0], acc);
                acc = fmaf(-a1, st[r][1], acc);
                acc = fmaf(-a2, st[r][2], acc);
                acc = fmaf(-a3, st[r][3], acc);
                acc = fmaf(-a4, st[r][4], acc);
                st[r][4] = st[r][3]; st[r][3] = st[r][2];
                st[r][2] = st[r][1]; st[r][1] = st[r][0];
                st[r][0] = acc;
            }
        }
        #pragma unroll
        for (int r = 0; r < 6; ++r)
            #pragma unroll
            for (int k = 0; k < 5; ++k)
                s_tail[lane][r * 5 + k] = st[r][k];
    } else if (tid == 192) {             // greedy adaptive chunk table
        const float stf = 99.0f / (float)(T_SAMPLES - 1);
        int c = 0, k = 0;
        while (c < T_SAMPLES) {
            s_cs[k] = c;
            int f = (int)((float)c * stf); if (f > 98) f = 98;
            int L = s_mf[f] + 1;
            if (L > LCAP) L = LCAP;
            c += L; ++k;
        }
        s_cs[k] = T_SAMPLES;
        s_nch = k;
    }
    __syncthreads();

    if (tid == 0) {   // chain 5-dim boundary states through 64 segments
        float Y[5] = {0.f, 0.f, 0.f, 0.f, 0.f};
        for (int l = 0; l < 64; ++l) {
            #pragma unroll
            for (int c = 0; c < 5; ++c) s_bound[l][c] = Y[c];
            float tl[30];
            #pragma unroll
            for (int j = 0; j < 30; ++j) tl[j] = s_tail[l][j];
            float ny[5];
            #pragma unroll
            for (int k = 0; k < 5; ++k) {
                float acc = tl[k];
                #pragma unroll
                for (int c = 1; c <= 5; ++c)
                    acc = fmaf(tl[c * 5 + k], Y[c - 1], acc);
                ny[k] = acc;
            }
            #pragma unroll
            for (int k = 0; k < 5; ++k) Y[k] = ny[k];
        }
    }
    __syncthreads();

    if (tid < 64) {   // re-run each segment with correct boundary state
        float b0 = s_bound[lane][0], b1 = s_bound[lane][1], b2 = s_bound[lane][2];
        float b3 = s_bound[lane][3], b4 = s_bound[lane][4];
        const float* ar = &s_a[lane][0];
        float* xr = &s_x[lane][0];
        #pragma unroll 8
        for (int i = 0; i < 32; ++i) {
            float a0 = ar[i * 5 + 0], a1 = ar[i * 5 + 1], a2 = ar[i * 5 + 2];
            float a3 = ar[i * 5 + 3], a4 = ar[i * 5 + 4];
            float acc = xr[i];
            acc = fmaf(-a0, b0, acc);
            acc = fmaf(-a1, b1, acc);
            acc = fmaf(-a2, b2, acc);
            acc = fmaf(-a3, b3, acc);
            acc = fmaf(-a4, b4, acc);
            b4 = b3; b3 = b2; b2 = b1; b1 = b0; b0 = acc;
            xr[i] = acc;
        }
    }
    __syncthreads();    // phase 1 done; s_big is now free for the coef ring

    // ---- phase 2: adaptive-chunk resonator, 256 threads ----
    const unsigned dumpA = 1032u + (unsigned)lane;
    const int NCH = s_nch;

    #define STAGE_BLK(b)                                                       \
    {                                                                          \
        float* dst_ = s_big + ((b) & 3) * BLKF + wv * 1536;                    \
        const float* src_ = ws + (size_t)(b) * BLKF + wv * 1536 + lane * 4;    \
        gload_lds16(src_ + 0 * 256, dst_ + 0 * 256);                           \
        gload_lds16(src_ + 1 * 256, dst_ + 1 * 256);                           \
        gload_lds16(src_ + 2 * 256, dst_ + 2 * 256);                           \
        gload_lds16(src_ + 3 * 256, dst_ + 3 * 256);                           \
        gload_lds16(src_ + 4 * 256, dst_ + 4 * 256);                           \
        gload_lds16(src_ + 5 * 256, dst_ + 5 * 256);                           \
    }

    // prefetch register sets A/B, 2 samples each
    float4 cm0_A0, cm1_A0, cm0_A1, cm1_A1;
    float4 cm0_B0, cm1_B0, cm0_B1, cm1_B1;
    unsigned cb2_A0, cb2_A1, cb2_B0, cb2_B1;
    float cx_A0, cx_A1, cx_B0, cx_B1;

    #define PREFETCH1(SET, IDX, SS)                                            \
    {                                                                          \
        int s_ = (SS);                                                         \
        int ad_ = (((s_ >> 9) & 3) * BLKF) + ((s_ & 511) * 12);                \
        const float4* q_ = (const float4*)(s_big + ad_);                       \
        cm0_##SET##IDX = q_[0];                                                \
        cm1_##SET##IDX = q_[1];                                                \
        cb2_##SET##IDX = ((unsigned)__float_as_int(q_[2].x)) & 1022u;          \
        cx_##SET##IDX = (s_ < cxlim_) ? s_x[(s_ >> 5) & 63][s_ & 31] : 0.0f;   \
    }
    #define PREFETCH(SET, C0N, C1N)                                            \
    {                                                                          \
        int cxlim_ = (C1N) < BURST ? (C1N) : BURST;                            \
        PREFETCH1(SET, 0, (C0N) + tid)                                         \
        PREFETCH1(SET, 1, (C0N) + 256 + tid)                                   \
    }

    #define COMPUTE1(SET, IDX, SS)                                             \
    {                                                                          \
        const int s_ = (SS);                                                   \
        const bool act_ = s_ < c1;                                             \
        const float2* w_ = (const float2*)(s_hist + cb2_##SET##IDX);           \
        const float2 h01 = w_[0], h23 = w_[1], h45 = w_[2], h67 = w_[3];       \
        const float4 m0 = cm0_##SET##IDX, m1 = cm1_##SET##IDX;                 \
        float acc = cx_##SET##IDX;                                             \
        acc = fmaf(m1.w, h67.y, acc);                                          \
        acc = fmaf(m1.z, h67.x, acc);                                          \
        acc = fmaf(m1.y, h45.y, acc);                                          \
        acc = fmaf(m1.x, h45.x, acc);                                          \
        acc = fmaf(m0.w, h23.y, acc);                                          \
        acc = fmaf(m0.z, h23.x, acc);                                          \
        acc = fmaf(m0.y, h01.y, acc);                                          \
        acc = fmaf(m0.x, h01.x, acc);                                          \
        const unsigned p_ = ((unsigned)s_) & 1023u;                            \
        s_hist[act_ ? p_ : dumpA] = acc;                                       \
        if (mir) s_hist[(act_ && p_ < 6u) ? (p_ + 1024u) : dumpA] = acc;       \
    }
    #define COMPUTE(SET)                                                       \
    { COMPUTE1(SET, 0, c0 + tid) COMPUTE1(SET, 1, c0 + 256 + tid) }

    // dump undumped ring range [LO, HI) to out (never waited on)
    #define DUMPR(LO, HI)                                                      \
    {                                                                          \
        int t_ = (LO) + tid;                                                   \
        if (t_ < (HI)) out[t_] = s_hist[((unsigned)t_) & 1023u];               \
        t_ += 256;                                                             \
        if (t_ < (HI)) out[t_] = s_hist[((unsigned)t_) & 1023u];               \
    }

    #define CHUNK_STEP(CUR, NXT, KK)                                           \
    {                                                                          \
        int kg_ = (KK) + 5; if (kg_ > NCH) kg_ = NCH;                          \
        int Sg_ = (s_cs[kg_] - 1) >> 9;                                        \
        while (S <= Sg_) { STAGE_BLK(S) ++S; }                                 \
        int k1_ = (KK) + 1; if (k1_ > NCH) k1_ = NCH;                          \
        int k2_ = (KK) + 2; if (k2_ > NCH) k2_ = NCH;                          \
        const int c0n_ = s_cs[k1_], c1n_ = s_cs[k2_];                          \
        if ((KK) + 1 < NCH) { PREFETCH(NXT, c0n_, c1n_) }                      \
        const bool mir = (((unsigned)c0 & 1023u) < 6u) ||                      \
                         (((c0 & 1023) + (c1 - c0)) > 1024);                   \
        COMPUTE(CUR)                                                           \
        DUMPR(dlo, c0)                                                         \
        dlo = c0;                                                              \
        {                                                                      \
            int k3_ = (KK) + 3; if (k3_ > NCH) k3_ = NCH;                      \
            int bn_ = (s_cs[k3_] - 1) >> 9;                                    \
            if (bn_ > Bpub) {                                                  \
                int nn_ = (S - 1) - bn_;                                       \
                if (nn_ <= 0)                                                  \
                    asm volatile("s_waitcnt vmcnt(0)" ::: "memory");           \
                else if (nn_ == 1)                                             \
                    asm volatile("s_waitcnt vmcnt(6)" ::: "memory");           \
                else if (nn_ == 2)                                             \
                    asm volatile("s_waitcnt vmcnt(12)" ::: "memory");          \
                else                                                           \
                    asm volatile("s_waitcnt vmcnt(18)" ::: "memory");          \
                Bpub = bn_;                                                    \
            }                                                                  \
        }                                                                      \
        asm volatile("s_waitcnt lgkmcnt(0)\n\ts_barrier" ::: "memory");        \
        c0 = c0n_; c1 = c1n_;                                                  \
    }

    // prologue: stage blocks covering chunks 0..3, publish, prefetch chunk 0
    int S = 0;
    int Bpub;
    {
        int k4 = NCH < 4 ? NCH : 4;
        int Sg = (s_cs[k4] - 1) >> 9;
        while (S <= Sg) { STAGE_BLK(S) ++S; }
        asm volatile("s_waitcnt vmcnt(0)" ::: "memory");
        Bpub = S - 1;
    }
    __syncthreads();

    int c0 = s_cs[0];
    int c1 = s_cs[NCH < 1 ? NCH : 1];
    int dlo = 0;
    PREFETCH(A, c0, c1)

    #pragma unroll 1
    for (int k = 0; k < NCH; k += 2) {
        CHUNK_STEP(A, B, k)
        if (k + 1 < NCH) { CHUNK_STEP(B, A, k + 1) }
    }

    // epilogue: dump the final chunk's range
    DUMPR(dlo, T_SAMPLES)

    #undef CHUNK_STEP
    #undef DUMPR
    #undef COMPUTE
    #undef COMPUTE1
    #undef PREFETCH
    #undef PREFETCH1
    #undef STAGE_BLK
}

// ------------------------------------------------- fallback (round-1 kernel)
#define CHUNK_FB  101
#define NCH_FB    ((T_SAMPLES + CHUNK_FB - 1) / CHUNK_FB)
#define HIST_FB   1024

__global__ __launch_bounds__(128) void diffks_fallback(
    const float* __restrict__ delay_frames,
    const float* __restrict__ excitation,
    const float* __restrict__ raw_coeff,
    const float* __restrict__ raw_gain,
    const float* __restrict__ exc_coeff,
    float* __restrict__ out)
{
    __shared__ float s_a[EXC_ORD][BURST];
    __shared__ float s_x[BURST];
    __shared__ float s_hist[HIST_FB];
    __shared__ __align__(16) float s_coef[NFRAMES][8];
    __shared__ float s_delay[NFRAMES];

    const int tid = threadIdx.x;
    const float gain = 0.1f / (1.0f + expf(-raw_gain[0])) + 0.9f;

    for (int i = tid; i < NFRAMES; i += 128) s_delay[i] = delay_frames[i];
    for (int f = tid; f < NFRAMES; f += 128) {
        float sb[NCOEF]; float s = 0.0f;
        #pragma unroll
        for (int j = 0; j < NCOEF; ++j) {
            sb[j] = 1.0f / (1.0f + expf(-raw_coeff[f * NCOEF + j]));
            s += sb[j];
        }
        float inv = gain / s;
        #pragma unroll
        for (int j = 0; j < NCOEF; ++j) s_coef[f][j] = sb[j] * inv;
        s_coef[f][6] = 0.0f; s_coef[f][7] = 0.0f;
    }
    const float stepE = 99.0f / 2047.0f;
    for (int t = tid; t < BURST; t += 128) {
        float pos = (float)t * stepE;
        int i0 = (int)pos; if (i0 > NFRAMES - 2) i0 = NFRAMES - 2;
        float w = pos - (float)i0;
        const float* c0 = exc_coeff + i0 * EXC_ORD;
        #pragma unroll
        for (int k = 0; k < EXC_ORD; ++k) {
            float a0 = c0[k], a1 = c0[k + EXC_ORD];
            s_a[k][t] = a0 + (a1 - a0) * w;
        }
        s_x[t] = excitation[t];
    }
    for (int i = tid; i < HIST_FB; i += 128) s_hist[i] = 0.0f;
    __syncthreads();

    if (tid == 0) {
        float y1 = 0.f, y2 = 0.f, y3 = 0.f, y4 = 0.f, y5 = 0.f;
        #pragma unroll 4
        for (int t = 0; t < BURST; ++t) {
            float p = s_x[t];
            p = fmaf(-s_a[1][t], y2, p);
            p = fmaf(-s_a[2][t], y3, p);
            p = fmaf(-s_a[3][t], y4, p);
            p = fmaf(-s_a[4][t], y5, p);
            float y = fmaf(-s_a[0][t], y1, p);
            s_x[t] = y;
            y5 = y4; y4 = y3; y3 = y2; y2 = y1; y1 = y;
        }
    }
    __syncthreads();

    const float stepT = 99.0f / (float)(T_SAMPLES - 1);
    for (int c = 0; c < NCH_FB; ++c) {
        int t = c * CHUNK_FB + tid;
        if (tid < CHUNK_FB && t < T_SAMPLES) {
            float pos = (float)t * stepT;
            int i0 = (int)pos; if (i0 > NFRAMES - 2) i0 = NFRAMES - 2;
            float w = pos - (float)i0;
            float d0 = s_delay[i0], d1 = s_delay[i0 + 1];
            float delay = d0 + (d1 - d0) * w;
            int z = (int)delay;
            float alfa = delay - (float)z;
            const float4* f0 = reinterpret_cast<const float4*>(s_coef[i0]);
            const float4* f1 = reinterpret_cast<const float4*>(s_coef[i0 + 1]);
            float4 c0a = f0[0], c0b = f0[1];
            float4 c1a = f1[0], c1b = f1[1];
            float b[NCOEF];
            b[0] = c0a.x + (c1a.x - c0a.x) * w;
            b[1] = c0a.y + (c1a.y - c0a.y) * w;
            b[2] = c0a.z + (c1a.z - c0a.z) * w;
            b[3] = c0a.w + (c1a.w - c0a.w) * w;
            b[4] = c0b.x + (c1b.x - c0b.x) * w;
            b[5] = c0b.y + (c1b.y - c0b.y) * w;
            float oma = 1.0f - alfa;
            float v[7];
            v[0] = -oma * b[0];
            #pragma unroll
            for (int j = 1; j <= 5; ++j) v[j] = -(alfa * b[j - 1] + oma * b[j]);
            v[6] = -alfa * b[5];
            float x = (t < BURST) ? s_x[t] : 0.0f;
            int base = t - z - 1;
            float sum = 0.0f;
            #pragma unroll
            for (int j = 0; j < 7; ++j) {
                int idx = base - j;
                float yv = s_hist[idx & (HIST_FB - 1)];
                if (idx < 0) yv = 0.0f;
                sum = fmaf(v[j], yv, sum);
            }
            float y = x - sum;
            s_hist[t & (HIST_FB - 1)] = y;
            out[t] = y;
        }
        __syncthreads();
    }
}

// ---------------------------------------------------------------- launch
extern "C" void kernel_launch(void* const* d_in, const int* in_sizes, int n_in,
                              void* d_out, int out_size, void* d_ws, size_t ws_size,
                              hipStream_t stream) {
    const float* delay_frames = (const float*)d_in[0];
    const float* excitation   = (const float*)d_in[1];
    const float* raw_coeff    = (const float*)d_in[2];
    const float* raw_gain     = (const float*)d_in[3];
    const float* exc_coeff    = (const float*)d_in[4];
    float* out = (float*)d_out;

    if (ws_size >= WS_TOTAL_BYTES) {
        float* ws = (float*)d_ws;
        int gridA = (T_SAMPLES + BURST + 255) / 256;
        diffks_precompute<<<gridA, 256, 0, stream>>>(delay_frames, raw_coeff,
                                                     raw_gain, exc_coeff, ws);
        diffks_serial<<<1, 256, 0, stream>>>(delay_frames, excitation, ws, out);
    } else {
        diffks_fallback<<<1, 128, 0, stream>>>(delay_frames, excitation,
                                               raw_coeff, raw_gain, exc_coeff, out);
    }
}

// Round 8
// 157.164 us; speedup vs baseline: 1.8844x; 1.8844x over previous
//
#include <hip/hip_runtime.h>
#include <math.h>

// DiffKS round 11.
// r9/r10 (adaptive chunking) regressed: per-step cost ~2000-2400 cy because
// all 4 waves (1 per SIMD, each latency-bound at ~8cy/instr) executed the
// full fat step. Reverting to r8's lean owner/prepper structure (650 cy/body,
// 119.5 us) and cutting its barrier count 441 -> 110:
//   * super-steps of 4 consecutive bodies owned by ONE wave. Body k+1's
//     window reads reach at most into body k (z >= 100), written by the SAME
//     wave -> ordering via s_waitcnt lgkmcnt(0) only; s_barrier needed only
//     between super-steps (ownership handoff).
//   * wave w owns super-step ss (ss&3==w); preps its next 4 bodies during
//     ss-1 (coefs+bases+x into named registers, from the LDS-staged group
//     double buffer, r8's proven pattern);
//   * staging: at even ss the free wave ((ss+2)&3) issues 38x global_load_lds
//     for group ss/2+1; it drains its own vmcnt before prepping from that
//     buffer at ss+1; other waves see the data after the intervening barrier.
// Per-sample math bit-identical to r7/r8 (aligned 8-slot windows, float2
// reads, same FMA order).

#define T_SAMPLES 44100
#define NFRAMES   100
#define NCOEF     6
#define BURST     2048
#define EXC_ORD   5

#define HISTSZ    1096          // 1024 ring + 6 mirror + pad + 64 dump slots
#define GRPF      9600          // 800 samples * 12 floats per group
#define CFBUF     9856          // 9728 staged (38x1KB) + 128 pad for reads

#define WS_COEF_FLOATS (T_SAMPLES * 12)
#define WS_EXC_OFF     WS_COEF_FLOATS
#define WS_EXC_FLOATS  (EXC_ORD * BURST)
#define WS_TOTAL_BYTES ((size_t)(WS_COEF_FLOATS + WS_EXC_FLOATS) * 4)

// ---------------------------------------------------------------- kernel A
__global__ __launch_bounds__(256) void diffks_precompute(
    const float* __restrict__ delay_frames,
    const float* __restrict__ raw_coeff,
    const float* __restrict__ raw_gain,
    const float* __restrict__ exc_coeff,
    float* __restrict__ ws)
{
    int g = blockIdx.x * 256 + threadIdx.x;
    const float gain = 0.1f / (1.0f + expf(-raw_gain[0])) + 0.9f;

    if (g < T_SAMPLES) {
        const float stepT = 99.0f / (float)(T_SAMPLES - 1);
        float pos = (float)g * stepT;
        int i0 = (int)pos; if (i0 > NFRAMES - 2) i0 = NFRAMES - 2;
        float w = pos - (float)i0;

        float d0 = delay_frames[i0], d1 = delay_frames[i0 + 1];
        float delay = d0 + (d1 - d0) * w;
        int z = (int)delay;                  // delay >= 100 > 0
        float alfa = delay - (float)z;

        float b[NCOEF];
        {
            float c0v[NCOEF], c1v[NCOEF];
            float s0 = 0.f, s1 = 0.f;
            #pragma unroll
            for (int j = 0; j < NCOEF; ++j) {
                c0v[j] = 1.0f / (1.0f + expf(-raw_coeff[i0 * NCOEF + j]));
                c1v[j] = 1.0f / (1.0f + expf(-raw_coeff[(i0 + 1) * NCOEF + j]));
                s0 += c0v[j]; s1 += c1v[j];
            }
            float g0 = gain / s0, g1 = gain / s1;
            #pragma unroll
            for (int j = 0; j < NCOEF; ++j) {
                float x0 = c0v[j] * g0, x1 = c1v[j] * g1;
                b[j] = x0 + (x1 - x0) * w;
            }
        }
        // v_j exactly as previous rounds (bit-identical), then negate (exact)
        float oma = 1.0f - alfa;
        float v0 = -oma * b[0];
        float v1 = -(alfa * b[0] + oma * b[1]);
        float v2 = -(alfa * b[1] + oma * b[2]);
        float v3 = -(alfa * b[2] + oma * b[3]);
        float v4 = -(alfa * b[3] + oma * b[4]);
        float v5 = -(alfa * b[4] + oma * b[5]);
        float v6 = -alfa * b[5];
        float pv0 = -v0, pv1 = -v1, pv2 = -v2, pv3 = -v3;
        float pv4 = -v4, pv5 = -v5, pv6 = -v6;

        int base = g - z - 1;
        int q = base - 6;                    // window = y[q .. q+6]
        int off = q & 1;
        unsigned b2 = ((unsigned)q) & 1022u; // (q & ~1) & 1023, 8B-aligned

        // shifted taps: m[off+6-j] = pv_j  (FMA iterates i = 7..0)
        float m0, m1, m2, m3, m4, m5, m6, m7;
        if (off) { m0 = 0.f; m1 = pv6; m2 = pv5; m3 = pv4;
                   m4 = pv3; m5 = pv2; m6 = pv1; m7 = pv0; }
        else     { m0 = pv6; m1 = pv5; m2 = pv4; m3 = pv3;
                   m4 = pv2; m5 = pv1; m6 = pv0; m7 = 0.f; }

        float4* o = (float4*)(ws + (size_t)g * 12);
        o[0] = make_float4(m0, m1, m2, m3);
        o[1] = make_float4(m4, m5, m6, m7);
        o[2] = make_float4(__int_as_float((int)b2), 0.f, 0.f, 0.f);
    } else if (g < T_SAMPLES + BURST) {
        int te = g - T_SAMPLES;
        const float stepE = 99.0f / (float)(BURST - 1);
        float pos = (float)te * stepE;
        int i0 = (int)pos; if (i0 > NFRAMES - 2) i0 = NFRAMES - 2;
        float w = pos - (float)i0;
        float* o = ws + WS_EXC_OFF + te * EXC_ORD;     // interleaved [t*5+k]
        #pragma unroll
        for (int k = 0; k < EXC_ORD; ++k) {
            float a0 = exc_coeff[i0 * EXC_ORD + k];
            float a1 = exc_coeff[(i0 + 1) * EXC_ORD + k];
            o[k] = a0 + (a1 - a0) * w;
        }
    }
}

// async global->LDS copy, 16B per lane; LDS base must be wave-uniform
__device__ __forceinline__ void gload_lds16(const float* g, float* l) {
    __builtin_amdgcn_global_load_lds(
        (const __attribute__((address_space(1))) unsigned int*)(g),
        (__attribute__((address_space(3))) unsigned int*)(l),
        16, 0, 0);
}

// ---------------------------------------------------------------- kernel B
__global__ __launch_bounds__(256, 1) void diffks_serial(
    const float* __restrict__ excitation,
    const float* __restrict__ ws,
    float* __restrict__ out)
{
    __shared__ float s_cf[2][CFBUF];     // coefficient double buffer (t-order)
    __shared__ float s_x[64][33];        // burst (padded rows)
    __shared__ float s_a[64][161];       // exc coefs [seg][(i%32)*5+k]
    __shared__ float s_hist[HISTSZ];     // 1024 ring + 6 mirror + 64 dump
    __shared__ float s_tail[64][32];
    __shared__ float s_bound[64][6];

    const int tid  = threadIdx.x;
    const int lane = tid & 63;
    const int wv   = tid >> 6;

    // ---- stage (all 256 threads) ----
    for (int t = tid; t < BURST; t += 256)
        s_x[t >> 5][t & 31] = excitation[t];
    for (int i = 0; i < 8; ++i) {        // exc coefs, 5 contiguous scalars
        int t = tid + i * 256;
        const float* g = ws + WS_EXC_OFF + t * EXC_ORD;
        float* dst = &s_a[t >> 5][(t & 31) * 5];
        dst[0] = g[0]; dst[1] = g[1]; dst[2] = g[2];
        dst[3] = g[3]; dst[4] = g[4];
    }
    for (int i = tid; i < HISTSZ; i += 256) s_hist[i] = 0.0f;
    __syncthreads();

    // ---- phase 1: excitation LPC via 64-segment state-space scan (wave 0) --
    if (tid < 64) {
        float st[6][5];
        #pragma unroll
        for (int r = 0; r < 6; ++r)
            #pragma unroll
            for (int k = 0; k < 5; ++k) st[r][k] = 0.0f;
        #pragma unroll
        for (int r = 1; r <= 5; ++r) st[r][r - 1] = 1.0f;

        const float* ar = &s_a[lane][0];
        const float* xr = &s_x[lane][0];
        #pragma unroll 8
        for (int i = 0; i < 32; ++i) {
            float a0 = ar[i * 5 + 0], a1 = ar[i * 5 + 1], a2 = ar[i * 5 + 2];
            float a3 = ar[i * 5 + 3], a4 = ar[i * 5 + 4];
            float xv = xr[i];
            #pragma unroll
            for (int r = 0; r < 6; ++r) {
                float acc = (r == 0) ? xv : 0.0f;
                acc = fmaf(-a0, st[r][0], acc);
                acc = fmaf(-a1, st[r][1], acc);
                acc = fmaf(-a2, st[r][2], acc);
                acc = fmaf(-a3, st[r][3], acc);
                acc = fmaf(-a4, st[r][4], acc);
                st[r][4] = st[r][3]; st[r][3] = st[r][2];
                st[r][2] = st[r][1]; st[r][1] = st[r][0];
                st[r][0] = acc;
            }
        }
        #pragma unroll
        for (int r = 0; r < 6; ++r)
            #pragma unroll
            for (int k = 0; k < 5; ++k)
                s_tail[lane][r * 5 + k] = st[r][k];
    }
    __syncthreads();

    if (tid == 0) {   // chain 5-dim boundary states through 64 segments
        float Y[5] = {0.f, 0.f, 0.f, 0.f, 0.f};
        for (int l = 0; l < 64; ++l) {
            #pragma unroll
            for (int c = 0; c < 5; ++c) s_bound[l][c] = Y[c];
            float tl[30];
            #pragma unroll
            for (int j = 0; j < 30; ++j) tl[j] = s_tail[l][j];
            float ny[5];
            #pragma unroll
            for (int k = 0; k < 5; ++k) {
                float acc = tl[k];
                #pragma unroll
                for (int c = 1; c <= 5; ++c)
                    acc = fmaf(tl[c * 5 + k], Y[c - 1], acc);
                ny[k] = acc;
            }
            #pragma unroll
            for (int k = 0; k < 5; ++k) Y[k] = ny[k];
        }
    }
    __syncthreads();

    if (tid < 64) {   // re-run each segment with correct boundary state
        float b0 = s_bound[lane][0], b1 = s_bound[lane][1], b2 = s_bound[lane][2];
        float b3 = s_bound[lane][3], b4 = s_bound[lane][4];
        const float* ar = &s_a[lane][0];
        float* xr = &s_x[lane][0];
        #pragma unroll 8
        for (int i = 0; i < 32; ++i) {
            float a0 = ar[i * 5 + 0], a1 = ar[i * 5 + 1], a2 = ar[i * 5 + 2];
            float a3 = ar[i * 5 + 3], a4 = ar[i * 5 + 4];
            float acc = xr[i];
            acc = fmaf(-a0, b0, acc);
            acc = fmaf(-a1, b1, acc);
            acc = fmaf(-a2, b2, acc);
            acc = fmaf(-a3, b3, acc);
            acc = fmaf(-a4, b4, acc);
            b4 = b3; b3 = b2; b2 = b1; b1 = b0; b0 = acc;
            xr[i] = acc;
        }
    }
    __syncthreads();

    // ---- phase 2: 4-wave round-robin, 4 bodies per super-step ----
    const bool lane_act = (lane < 50);
    const unsigned dumpA = 1032u + (unsigned)lane;   // per-lane dump slot

    #define STAGE_GRP(gg)                                                      \
    {                                                                          \
        float* dstb = &s_cf[(gg) & 1][0];                                      \
        const float* srcb = ws + (size_t)(gg) * GRPF + lane * 4;               \
        const int nis = ((gg) >= 55) ? 5 : 38;                                 \
        for (int i = 0; i < nis; ++i)                                          \
            gload_lds16(srcb + i * 256, dstb + i * 256);                       \
    }

    // prep register sets: 4 bodies, named (no runtime-indexed arrays)
    float4 p0a0, p0a1, p0b0, p0b1, p1a0, p1a1, p1b0, p1b1;
    float4 p2a0, p2a1, p2b0, p2b1, p3a0, p3a1, p3b0, p3b1;
    unsigned q0A, q0B, q1A, q1B, q2A, q2B, q3A, q3B;
    float x0A, x0B, x1A, x1B, x2A, x2B, x3A, x3B;

    #define PREPJ(J, BB)                                                       \
    {                                                                          \
        int b_ = (BB); if (b_ > 440) b_ = 440;                                 \
        const float* bu_ = &s_cf[(b_ >> 3) & 1][0];                            \
        const int ln_ = (b_ & 7) * 100 + lane;                                 \
        const float4* qA_ = (const float4*)(bu_ + ln_ * 12);                   \
        const float4* qB_ = (const float4*)(bu_ + (ln_ + 50) * 12);            \
        p##J##a0 = qA_[0]; p##J##a1 = qA_[1];                                  \
        q##J##A = (unsigned)__float_as_int(qA_[2].x);                          \
        p##J##b0 = qB_[0]; p##J##b1 = qB_[1];                                  \
        q##J##B = (unsigned)__float_as_int(qB_[2].x);                          \
        const int tA_ = b_ * 100 + lane;                                       \
        const int tB_ = tA_ + 50;                                              \
        x##J##A = (lane_act && tA_ < BURST)                                    \
                      ? s_x[(tA_ >> 5) & 63][tA_ & 31] : 0.0f;                 \
        x##J##B = (lane_act && tB_ < BURST)                                    \
                      ? s_x[(tB_ >> 5) & 63][tB_ & 31] : 0.0f;                 \
    }

    #define PREP4(SS)                                                          \
    {                                                                          \
        const int sb_ = (SS) * 4;                                              \
        PREPJ(0, sb_ + 0) PREPJ(1, sb_ + 1)                                    \
        PREPJ(2, sb_ + 2) PREPJ(3, sb_ + 3)                                    \
    }

    // one body: window reads -> 16 FMA (r8 order) -> ring writes -> rare
    // mirror -> out stores -> lgkmcnt(0) (orders writes before next body's
    // reads within the same wave; sched_barrier pins it)
    #define CBODY(J, BB)                                                       \
    {                                                                          \
        const int t0_ = (BB) * 100;                                            \
        const int tA_ = t0_ + lane;                                            \
        const int tB_ = tA_ + 50;                                              \
        const float2* wA_ = (const float2*)(s_hist + q##J##A);                 \
        const float2* wB_ = (const float2*)(s_hist + q##J##B);                 \
        const float2 a01_ = wA_[0], a23_ = wA_[1];                             \
        const float2 a45_ = wA_[2], a67_ = wA_[3];                             \
        const float2 b01_ = wB_[0], b23_ = wB_[1];                             \
        const float2 b45_ = wB_[2], b67_ = wB_[3];                             \
        const float4 am0_ = p##J##a0, am1_ = p##J##a1;                         \
        const float4 bm0_ = p##J##b0, bm1_ = p##J##b1;                         \
        float accA = x##J##A, accB = x##J##B;                                  \
        accA = fmaf(am1_.w, a67_.y, accA);  accB = fmaf(bm1_.w, b67_.y, accB); \
        accA = fmaf(am1_.z, a67_.x, accA);  accB = fmaf(bm1_.z, b67_.x, accB); \
        accA = fmaf(am1_.y, a45_.y, accA);  accB = fmaf(bm1_.y, b45_.y, accB); \
        accA = fmaf(am1_.x, a45_.x, accA);  accB = fmaf(bm1_.x, b45_.x, accB); \
        accA = fmaf(am0_.w, a23_.y, accA);  accB = fmaf(bm0_.w, b23_.y, accB); \
        accA = fmaf(am0_.z, a23_.x, accA);  accB = fmaf(bm0_.z, b23_.x, accB); \
        accA = fmaf(am0_.y, a01_.y, accA);  accB = fmaf(bm0_.y, b01_.y, accB); \
        accA = fmaf(am0_.x, a01_.x, accA);  accB = fmaf(bm0_.x, b01_.x, accB); \
        const unsigned pA_ = ((unsigned)tA_) & 1023u;                          \
        const unsigned pB_ = ((unsigned)tB_) & 1023u;                          \
        s_hist[lane_act ? pA_ : dumpA] = accA;                                 \
        s_hist[lane_act ? pB_ : dumpA] = accB;                                 \
        {                                                                      \
            const unsigned pm_ = ((unsigned)t0_) & 1023u;                      \
            if (pm_ >= 924u || pm_ < 6u) {                                     \
                s_hist[(lane_act && pA_ < 6u) ? (pA_ + 1024u) : dumpA] = accA; \
                s_hist[(lane_act && pB_ < 6u) ? (pB_ + 1024u) : dumpA] = accB; \
            }                                                                  \
        }                                                                      \
        if (lane_act) { out[tA_] = accA; out[tB_] = accB; }                    \
        asm volatile("s_waitcnt lgkmcnt(0)" ::: "memory");                     \
        __builtin_amdgcn_sched_barrier(0);                                     \
    }

    #define COMPUTE4(SS)                                                       \
    {                                                                          \
        const int fb_ = (SS) * 4;                                              \
        CBODY(0, fb_ + 0) CBODY(1, fb_ + 1)                                    \
        CBODY(2, fb_ + 2) CBODY(3, fb_ + 3)                                    \
    }

    // prologue: stage group 0 (wave 1), publish, wave 0 preps super-step 0
    if (wv == 1) {
        STAGE_GRP(0)
        asm volatile("s_waitcnt vmcnt(0)" ::: "memory");
    }
    __syncthreads();
    if (wv == 0) { PREP4(0) }
    __syncthreads();

    // main loop: 110 super-steps (bodies 0..439)
    //   owner (ss&3) computes 4 bodies; at even ss the free wave ((ss+2)&3)
    //   stages group ss/2+1; prepper ((ss+1)&3) drains its own vmcnt and
    //   preps super-step ss+1; one barrier per super-step.
    #pragma unroll 1
    for (int ss = 0; ss < 110; ++ss) {
        if (wv == (ss & 3)) { COMPUTE4(ss) }
        if (((ss & 1) == 0) && (ss <= 108) && (wv == ((ss + 2) & 3))) {
            STAGE_GRP((ss >> 1) + 1)
        }
        if (wv == ((ss + 1) & 3)) {
            asm volatile("s_waitcnt vmcnt(0)" ::: "memory");
            PREP4(ss + 1)
        }
        asm volatile("s_waitcnt lgkmcnt(0)\n\ts_barrier" ::: "memory");
    }
    // tail body 440 (super-step 110, owner wave 2, prepped during ss=109)
    if (wv == 2) { CBODY(0, 440) }

    #undef COMPUTE4
    #undef CBODY
    #undef PREP4
    #undef PREPJ
    #undef STAGE_GRP
}

// ------------------------------------------------- fallback (round-1 kernel)
#define CHUNK_FB  101
#define NCH_FB    ((T_SAMPLES + CHUNK_FB - 1) / CHUNK_FB)
#define HIST_FB   1024

__global__ __launch_bounds__(128) void diffks_fallback(
    const float* __restrict__ delay_frames,
    const float* __restrict__ excitation,
    const float* __restrict__ raw_coeff,
    const float* __restrict__ raw_gain,
    const float* __restrict__ exc_coeff,
    float* __restrict__ out)
{
    __shared__ float s_a[EXC_ORD][BURST];
    __shared__ float s_x[BURST];
    __shared__ float s_hist[HIST_FB];
    __shared__ __align__(16) float s_coef[NFRAMES][8];
    __shared__ float s_delay[NFRAMES];

    const int tid = threadIdx.x;
    const float gain = 0.1f / (1.0f + expf(-raw_gain[0])) + 0.9f;

    for (int i = tid; i < NFRAMES; i += 128) s_delay[i] = delay_frames[i];
    for (int f = tid; f < NFRAMES; f += 128) {
        float sb[NCOEF]; float s = 0.0f;
        #pragma unroll
        for (int j = 0; j < NCOEF; ++j) {
            sb[j] = 1.0f / (1.0f + expf(-raw_coeff[f * NCOEF + j]));
            s += sb[j];
        }
        float inv = gain / s;
        #pragma unroll
        for (int j = 0; j < NCOEF; ++j) s_coef[f][j] = sb[j] * inv;
        s_coef[f][6] = 0.0f; s_coef[f][7] = 0.0f;
    }
    const float stepE = 99.0f / 2047.0f;
    for (int t = tid; t < BURST; t += 128) {
        float pos = (float)t * stepE;
        int i0 = (int)pos; if (i0 > NFRAMES - 2) i0 = NFRAMES - 2;
        float w = pos - (float)i0;
        const float* c0 = exc_coeff + i0 * EXC_ORD;
        #pragma unroll
        for (int k = 0; k < EXC_ORD; ++k) {
            float a0 = c0[k], a1 = c0[k + EXC_ORD];
            s_a[k][t] = a0 + (a1 - a0) * w;
        }
        s_x[t] = excitation[t];
    }
    for (int i = tid; i < HIST_FB; i += 128) s_hist[i] = 0.0f;
    __syncthreads();

    if (tid == 0) {
        float y1 = 0.f, y2 = 0.f, y3 = 0.f, y4 = 0.f, y5 = 0.f;
        #pragma unroll 4
        for (int t = 0; t < BURST; ++t) {
            float p = s_x[t];
            p = fmaf(-s_a[1][t], y2, p);
            p = fmaf(-s_a[2][t], y3, p);
            p = fmaf(-s_a[3][t], y4, p);
            p = fmaf(-s_a[4][t], y5, p);
            float y = fmaf(-s_a[0][t], y1, p);
            s_x[t] = y;
            y5 = y4; y4 = y3; y3 = y2; y2 = y1; y1 = y;
        }
    }
    __syncthreads();

    const float stepT = 99.0f / (float)(T_SAMPLES - 1);
    for (int c = 0; c < NCH_FB; ++c) {
        int t = c * CHUNK_FB + tid;
        if (tid < CHUNK_FB && t < T_SAMPLES) {
            float pos = (float)t * stepT;
            int i0 = (int)pos; if (i0 > NFRAMES - 2) i0 = NFRAMES - 2;
            float w = pos - (float)i0;
            float d0 = s_delay[i0], d1 = s_delay[i0 + 1];
            float delay = d0 + (d1 - d0) * w;
            int z = (int)delay;
            float alfa = delay - (float)z;
            const float4* f0 = reinterpret_cast<const float4*>(s_coef[i0]);
            const float4* f1 = reinterpret_cast<const float4*>(s_coef[i0 + 1]);
            float4 c0a = f0[0], c0b = f0[1];
            float4 c1a = f1[0], c1b = f1[1];
            float b[NCOEF];
            b[0] = c0a.x + (c1a.x - c0a.x) * w;
            b[1] = c0a.y + (c1a.y - c0a.y) * w;
            b[2] = c0a.z + (c1a.z - c0a.z) * w;
            b[3] = c0a.w + (c1a.w - c0a.w) * w;
            b[4] = c0b.x + (c1b.x - c0b.x) * w;
            b[5] = c0b.y + (c1b.y - c0b.y) * w;
            float oma = 1.0f - alfa;
            float v[7];
            v[0] = -oma * b[0];
            #pragma unroll
            for (int j = 1; j <= 5; ++j) v[j] = -(alfa * b[j - 1] + oma * b[j]);
            v[6] = -alfa * b[5];
            float x = (t < BURST) ? s_x[t] : 0.0f;
            int base = t - z - 1;
            float sum = 0.0f;
            #pragma unroll
            for (int j = 0; j < 7; ++j) {
                int idx = base - j;
                float yv = s_hist[idx & (HIST_FB - 1)];
                if (idx < 0) yv = 0.0f;
                sum = fmaf(v[j], yv, sum);
            }
            float y = x - sum;
            s_hist[t & (HIST_FB - 1)] = y;
            out[t] = y;
        }
        __syncthreads();
    }
}

// ---------------------------------------------------------------- launch
extern "C" void kernel_launch(void* const* d_in, const int* in_sizes, int n_in,
                              void* d_out, int out_size, void* d_ws, size_t ws_size,
                              hipStream_t stream) {
    const float* delay_frames = (const float*)d_in[0];
    const float* excitation   = (const float*)d_in[1];
    const float* raw_coeff    = (const float*)d_in[2];
    const float* raw_gain     = (const float*)d_in[3];
    const float* exc_coeff    = (const float*)d_in[4];
    float* out = (float*)d_out;

    if (ws_size >= WS_TOTAL_BYTES) {
        float* ws = (float*)d_ws;
        int gridA = (T_SAMPLES + BURST + 255) / 256;
        diffks_precompute<<<gridA, 256, 0, stream>>>(delay_frames, raw_coeff,
                                                     raw_gain, exc_coeff, ws);
        diffks_serial<<<1, 256, 0, stream>>>(excitation, ws, out);
    } else {
        diffks_fallback<<<1, 128, 0, stream>>>(delay_frames, excitation,
                                               raw_coeff, raw_gain, exc_coeff, out);
    }
}